// Round 1
// baseline (701.100 us; speedup 1.0000x reference)
//
#include <hip/hip_runtime.h>

#define N_NODES 50000
#define N_EDGES 800000
#define N_TOT   850000
#define NEG 0.2f

__device__ __forceinline__ float leaky(float x) { return x > 0.f ? x : NEG * x; }

// ---------------- GEMM1: xw1 = x[50000,256] @ W1[256,64]; fused al1_src/al1_dst ----------------
__global__ __launch_bounds__(256) void gemm1_k(const float* __restrict__ x,
    const float* __restrict__ W1, const float* __restrict__ a1s, const float* __restrict__ a1d,
    float* __restrict__ xw1, float* __restrict__ al1s, float* __restrict__ al1d)
{
  __shared__ float Wl[256 * 64];   // 64 KB
  for (int i = threadIdx.x; i < 256 * 64; i += 256) Wl[i] = W1[i];
  __syncthreads();
  const int lane = threadIdx.x & 63, wave = threadIdx.x >> 6;
  const float as = a1s[lane], adv = a1d[lane];   // lane = h*8+o maps a[h][o]
  for (int n = blockIdx.x * 4 + wave; n < N_NODES; n += gridDim.x * 4) {
    const float4* xr = (const float4*)(x + (size_t)n * 256);
    float acc = 0.f;
#pragma unroll 8
    for (int kc = 0; kc < 64; ++kc) {
      float4 xv = xr[kc];                         // broadcast load (same addr all lanes)
      const float* wp = &Wl[kc * 4 * 64 + lane];
      acc += xv.x * wp[0];
      acc += xv.y * wp[64];
      acc += xv.z * wp[128];
      acc += xv.w * wp[192];
    }
    xw1[n * 64 + lane] = acc;
    float ps = acc * as, pd = acc * adv;
    ps += __shfl_xor(ps, 1); ps += __shfl_xor(ps, 2); ps += __shfl_xor(ps, 4);
    pd += __shfl_xor(pd, 1); pd += __shfl_xor(pd, 2); pd += __shfl_xor(pd, 4);
    if ((lane & 7) == 0) { al1s[n * 8 + (lane >> 3)] = ps; al1d[n * 8 + (lane >> 3)] = pd; }
  }
}

// ---------------- GEMM2: xw2 = h1[50000,64] @ W2[64,128]; fused al2_src/al2_dst ----------------
__global__ __launch_bounds__(256) void gemm2_k(const float* __restrict__ h1,
    const float* __restrict__ W2, const float* __restrict__ a2s, const float* __restrict__ a2d,
    float* __restrict__ xw2, float* __restrict__ al2s, float* __restrict__ al2d)
{
  __shared__ float Wl[64 * 128];   // 32 KB
  for (int i = threadIdx.x; i < 64 * 128; i += 256) Wl[i] = W2[i];
  __syncthreads();
  const int lane = threadIdx.x & 63, wave = threadIdx.x >> 6;
  const float asx = a2s[2 * lane], asy = a2s[2 * lane + 1];
  const float adx = a2d[2 * lane], ady = a2d[2 * lane + 1];
  for (int n = blockIdx.x * 4 + wave; n < N_NODES; n += gridDim.x * 4) {
    const float4* hr = (const float4*)(h1 + (size_t)n * 64);
    float ax = 0.f, ay = 0.f;
#pragma unroll
    for (int kc = 0; kc < 16; ++kc) {
      float4 xv = hr[kc];
      const float* wp = &Wl[kc * 4 * 128 + 2 * lane];
      ax += xv.x * wp[0];   ay += xv.x * wp[1];
      ax += xv.y * wp[128]; ay += xv.y * wp[129];
      ax += xv.z * wp[256]; ay += xv.z * wp[257];
      ax += xv.w * wp[384]; ay += xv.w * wp[385];
    }
    float2 st; st.x = ax; st.y = ay;
    ((float2*)xw2)[n * 64 + lane] = st;
    float ps = ax * asx + ay * asy, pd = ax * adx + ay * ady;
    ps += __shfl_xor(ps, 1); ps += __shfl_xor(ps, 2); ps += __shfl_xor(ps, 4);
    pd += __shfl_xor(pd, 1); pd += __shfl_xor(pd, 2); pd += __shfl_xor(pd, 4);
    if ((lane & 7) == 0) { al2s[n * 8 + (lane >> 3)] = ps; al2d[n * 8 + (lane >> 3)] = pd; }
  }
}

// ---------------- CSR build ----------------
__global__ void count_k(const int* __restrict__ dstA, int* __restrict__ cnt) {
  int e = blockIdx.x * 256 + threadIdx.x;
  if (e < N_EDGES) atomicAdd(&cnt[dstA[e]], 1);
}

__global__ __launch_bounds__(1024) void scan_k(const int* __restrict__ cnt,
    int* __restrict__ rowst, int* __restrict__ cursor)
{
  __shared__ int sums[1024];
  const int tid = threadIdx.x;
  const int CH = (N_NODES + 1023) / 1024;   // 49
  int beg = tid * CH, end = beg + CH; if (end > N_NODES) end = N_NODES;
  int s = 0;
  for (int i = beg; i < end && i < N_NODES; ++i) s += cnt[i];
  sums[tid] = s;
  __syncthreads();
  for (int off = 1; off < 1024; off <<= 1) {
    int v = (tid >= off) ? sums[tid - off] : 0;
    __syncthreads();
    sums[tid] += v;
    __syncthreads();
  }
  int pre = (tid > 0) ? sums[tid - 1] : 0;   // exclusive prefix of this chunk
  for (int i = beg; i < end && i < N_NODES; ++i) {
    rowst[i] = pre; cursor[i] = pre; pre += cnt[i];
  }
}

__global__ void scatter_k(const int* __restrict__ srcA, const int* __restrict__ dstA,
    int* __restrict__ cursor, int* __restrict__ csr)
{
  int e = blockIdx.x * 256 + threadIdx.x;
  if (e < N_EDGES) {
    int d = dstA[e];
    int p = atomicAdd(&cursor[d], 1);
    csr[p] = srcA[e];
  }
}

// ---------------- Layer-1 aggregation: wave per node, online softmax ----------------
__global__ __launch_bounds__(256) void agg1_k(const float* __restrict__ xw1,
    const float* __restrict__ al1s, const float* __restrict__ al1d,
    const int* __restrict__ rowst, const int* __restrict__ cnt, const int* __restrict__ csr,
    const float* __restrict__ b1, float* __restrict__ h1,
    float* __restrict__ m1, float* __restrict__ den1)
{
  const int lane = threadIdx.x & 63;
  const int n = blockIdx.x * 4 + (threadIdx.x >> 6);
  if (n >= N_NODES) return;
  const int h = lane >> 3;
  const float ad = al1d[n * 8 + h];
  // self-loop initializes the online softmax
  float m = leaky(al1s[n * 8 + h] + ad);
  float den = 1.f;
  float acc = xw1[n * 64 + lane];
  const int beg = rowst[n], num = cnt[n];
  for (int i = 0; i < num; ++i) {
    const int s = csr[beg + i];
    float l = leaky(al1s[s * 8 + h] + ad);
    float mn = fmaxf(m, l);
    float sc = __expf(m - mn);
    float w  = __expf(l - mn);
    den = den * sc + w;
    acc = acc * sc + w * xw1[s * 64 + lane];
    m = mn;
  }
  if ((lane & 7) == 0) { m1[n * 8 + h] = m; den1[n * 8 + h] = den; }
  float o = acc / (den + 1e-16f) + b1[lane];
  h1[n * 64 + lane] = o > 0.f ? o : (__expf(o) - 1.f);   // ELU
}

// ---------------- alpha1 output: one thread per (edge, head) ----------------
__global__ void alpha_k(const int* __restrict__ srcA, const int* __restrict__ dstA,
    const float* __restrict__ al1s, const float* __restrict__ al1d,
    const float* __restrict__ m1, const float* __restrict__ den1,
    float* __restrict__ alpha_out)
{
  long long t = (long long)blockIdx.x * 256 + threadIdx.x;
  if (t >= (long long)N_TOT * 8) return;
  int e = (int)(t >> 3), h = (int)(t & 7);
  int s, d;
  if (e < N_EDGES) { s = srcA[e]; d = dstA[e]; }
  else             { s = d = e - N_EDGES; }
  float l = leaky(al1s[s * 8 + h] + al1d[d * 8 + h]);
  float a = __expf(l - m1[d * 8 + h]) / (den1[d * 8 + h] + 1e-16f);
  alpha_out[t] = a;
}

// ---------------- Layer-2 aggregation + log_softmax: wave per node ----------------
__global__ __launch_bounds__(256) void agg2_k(const float* __restrict__ xw2,
    const float* __restrict__ al2s, const float* __restrict__ al2d,
    const int* __restrict__ rowst, const int* __restrict__ cnt, const int* __restrict__ csr,
    const float* __restrict__ b2, float* __restrict__ logp)
{
  const int lane = threadIdx.x & 63;
  const int n = blockIdx.x * 4 + (threadIdx.x >> 6);
  if (n >= N_NODES) return;
  const int h = lane >> 3;                 // f = 2*lane, head = f/16
  const float ad = al2d[n * 8 + h];
  float m = leaky(al2s[n * 8 + h] + ad);
  float den = 1.f;
  const float2* xw2v = (const float2*)xw2;
  float2 a0 = xw2v[n * 64 + lane];
  float ax = a0.x, ay = a0.y;
  const int beg = rowst[n], num = cnt[n];
  for (int i = 0; i < num; ++i) {
    const int s = csr[beg + i];
    float l = leaky(al2s[s * 8 + h] + ad);
    float mn = fmaxf(m, l);
    float sc = __expf(m - mn);
    float w  = __expf(l - mn);
    den = den * sc + w;
    float2 xv = xw2v[s * 64 + lane];
    ax = ax * sc + w * xv.x;
    ay = ay * sc + w * xv.y;
    m = mn;
  }
  float inv = 1.f / (den + 1e-16f);
  float o0 = ax * inv + b2[2 * lane];
  float o1 = ay * inv + b2[2 * lane + 1];
  // log_softmax over all 128 features (2 per lane, 64 lanes)
  float mx = fmaxf(o0, o1);
#pragma unroll
  for (int off = 1; off < 64; off <<= 1) mx = fmaxf(mx, __shfl_xor(mx, off));
  float se = __expf(o0 - mx) + __expf(o1 - mx);
#pragma unroll
  for (int off = 1; off < 64; off <<= 1) se += __shfl_xor(se, off);
  float lse = mx + __logf(se);
  float2 o; o.x = o0 - lse; o.y = o1 - lse;
  ((float2*)logp)[n * 64 + lane] = o;
}

extern "C" void kernel_launch(void* const* d_in, const int* in_sizes, int n_in,
                              void* d_out, int out_size, void* d_ws, size_t ws_size,
                              hipStream_t stream)
{
  const float* x   = (const float*)d_in[0];
  const int*   ei  = (const int*)d_in[1];     // [2, 800000] int32 (JAX x64 disabled)
  const float* W1  = (const float*)d_in[2];
  const float* a1s = (const float*)d_in[3];
  const float* a1d = (const float*)d_in[4];
  const float* b1  = (const float*)d_in[5];
  const float* W2  = (const float*)d_in[6];
  const float* a2s = (const float*)d_in[7];
  const float* a2d = (const float*)d_in[8];
  const float* b2  = (const float*)d_in[9];
  const int* srcA = ei;
  const int* dstA = ei + N_EDGES;

  float* ws    = (float*)d_ws;
  float* xw1   = ws;                   // 3,200,000
  float* h1    = xw1 + 3200000;        // 3,200,000
  float* xw2   = h1 + 3200000;         // 6,400,000
  float* al1s_ = xw2 + 6400000;        // 400,000
  float* al1d_ = al1s_ + 400000;
  float* m1    = al1d_ + 400000;
  float* den1  = m1 + 400000;
  float* al2s_ = den1 + 400000;
  float* al2d_ = al2s_ + 400000;
  int* cnt    = (int*)(al2d_ + 400000);
  int* rowst  = cnt + N_NODES;
  int* cursor = rowst + N_NODES;
  int* csr    = cursor + N_NODES;      // 800,000

  float* logp      = (float*)d_out;
  float* alpha_out = logp + (size_t)N_NODES * 128;

  hipMemsetAsync(cnt, 0, N_NODES * sizeof(int), stream);

  gemm1_k<<<1024, 256, 0, stream>>>(x, W1, a1s, a1d, xw1, al1s_, al1d_);
  count_k<<<(N_EDGES + 255) / 256, 256, 0, stream>>>(dstA, cnt);
  scan_k<<<1, 1024, 0, stream>>>(cnt, rowst, cursor);
  scatter_k<<<(N_EDGES + 255) / 256, 256, 0, stream>>>(srcA, dstA, cursor, csr);
  agg1_k<<<(N_NODES + 3) / 4, 256, 0, stream>>>(xw1, al1s_, al1d_, rowst, cnt, csr, b1, h1, m1, den1);
  alpha_k<<<(N_TOT * 8 + 255) / 256, 256, 0, stream>>>(srcA, dstA, al1s_, al1d_, m1, den1, alpha_out);
  gemm2_k<<<1024, 256, 0, stream>>>(h1, W2, a2s, a2d, xw2, al2s_, al2d_);
  agg2_k<<<(N_NODES + 3) / 4, 256, 0, stream>>>(xw2, al2s_, al2d_, rowst, cnt, csr, b2, logp);
}

// Round 2
// 571.097 us; speedup vs baseline: 1.2276x; 1.2276x over previous
//
#include <hip/hip_runtime.h>

#define N_NODES 50000
#define N_EDGES 800000
#define N_TOT   850000
#define NEG 0.2f

__device__ __forceinline__ float leaky(float x) { return x > 0.f ? x : NEG * x; }

// ---------------- GEMM1: xw1 = x[50000,256] @ W1[256,64]; fused al1_src/al1_dst ----------------
// 4 nodes per wave: LDS W-reads shared across nodes, 8 independent FMA chains.
__global__ __launch_bounds__(256) void gemm1_k(const float* __restrict__ x,
    const float* __restrict__ W1, const float* __restrict__ a1s, const float* __restrict__ a1d,
    float* __restrict__ xw1, float* __restrict__ al1s, float* __restrict__ al1d)
{
  __shared__ float Wl[256 * 64];   // 64 KB -> 2 blocks/CU
  for (int i = threadIdx.x; i < 256 * 64; i += 256) Wl[i] = W1[i];
  __syncthreads();
  const int lane = threadIdx.x & 63, wave = threadIdx.x >> 6;
  const int wid = blockIdx.x * 4 + wave, nw = gridDim.x * 4;
  const float as = a1s[lane], adv = a1d[lane];
  for (int n0 = wid * 4; n0 < N_NODES; n0 += nw * 4) {   // 50000 % 4 == 0
    const float4* xr0 = (const float4*)(x + (size_t)n0 * 256);
    const float4* xr1 = (const float4*)(x + (size_t)(n0 + 1) * 256);
    const float4* xr2 = (const float4*)(x + (size_t)(n0 + 2) * 256);
    const float4* xr3 = (const float4*)(x + (size_t)(n0 + 3) * 256);
    float a00 = 0.f, a01 = 0.f, a10 = 0.f, a11 = 0.f;
    float a20 = 0.f, a21 = 0.f, a30 = 0.f, a31 = 0.f;
#pragma unroll 2
    for (int kc = 0; kc < 64; ++kc) {
      const float* wr = &Wl[kc * 256 + lane];
      float w0 = wr[0], w1 = wr[64], w2 = wr[128], w3 = wr[192];
      float4 v0 = xr0[kc], v1 = xr1[kc], v2 = xr2[kc], v3 = xr3[kc];
      a00 += v0.x * w0 + v0.z * w2;  a01 += v0.y * w1 + v0.w * w3;
      a10 += v1.x * w0 + v1.z * w2;  a11 += v1.y * w1 + v1.w * w3;
      a20 += v2.x * w0 + v2.z * w2;  a21 += v2.y * w1 + v2.w * w3;
      a30 += v3.x * w0 + v3.z * w2;  a31 += v3.y * w1 + v3.w * w3;
    }
    float acc[4] = { a00 + a01, a10 + a11, a20 + a21, a30 + a31 };
#pragma unroll
    for (int j = 0; j < 4; ++j) {
      int n = n0 + j;
      xw1[(size_t)n * 64 + lane] = acc[j];
      float ps = acc[j] * as, pd = acc[j] * adv;
      ps += __shfl_xor(ps, 1); ps += __shfl_xor(ps, 2); ps += __shfl_xor(ps, 4);
      pd += __shfl_xor(pd, 1); pd += __shfl_xor(pd, 2); pd += __shfl_xor(pd, 4);
      if ((lane & 7) == 0) { al1s[n * 8 + (lane >> 3)] = ps; al1d[n * 8 + (lane >> 3)] = pd; }
    }
  }
}

// ---------------- GEMM2: xw2 = h1[50000,64] @ W2[64,128]; fused al2_src/al2_dst ----------------
__global__ __launch_bounds__(256) void gemm2_k(const float* __restrict__ h1,
    const float* __restrict__ W2, const float* __restrict__ a2s, const float* __restrict__ a2d,
    float* __restrict__ xw2, float* __restrict__ al2s, float* __restrict__ al2d)
{
  __shared__ float Wl[64 * 128];   // 32 KB
  for (int i = threadIdx.x; i < 64 * 128; i += 256) Wl[i] = W2[i];
  __syncthreads();
  const int lane = threadIdx.x & 63, wave = threadIdx.x >> 6;
  const int wid = blockIdx.x * 4 + wave, nw = gridDim.x * 4;
  const float asx = a2s[2 * lane], asy = a2s[2 * lane + 1];
  const float adx = a2d[2 * lane], ady = a2d[2 * lane + 1];
  const float2* Wv = (const float2*)Wl;   // Wv[k*64 + lane] = W2[k, 2*lane..2*lane+1]
  for (int n0 = wid * 4; n0 < N_NODES; n0 += nw * 4) {
    const float4* hr0 = (const float4*)(h1 + (size_t)n0 * 64);
    const float4* hr1 = (const float4*)(h1 + (size_t)(n0 + 1) * 64);
    const float4* hr2 = (const float4*)(h1 + (size_t)(n0 + 2) * 64);
    const float4* hr3 = (const float4*)(h1 + (size_t)(n0 + 3) * 64);
    float x0 = 0.f, y0 = 0.f, x1 = 0.f, y1 = 0.f;
    float x2 = 0.f, y2 = 0.f, x3 = 0.f, y3 = 0.f;
#pragma unroll 2
    for (int kc = 0; kc < 16; ++kc) {
      float2 wq0 = Wv[(4 * kc + 0) * 64 + lane];
      float2 wq1 = Wv[(4 * kc + 1) * 64 + lane];
      float2 wq2 = Wv[(4 * kc + 2) * 64 + lane];
      float2 wq3 = Wv[(4 * kc + 3) * 64 + lane];
      float4 v0 = hr0[kc], v1 = hr1[kc], v2 = hr2[kc], v3 = hr3[kc];
      x0 += v0.x * wq0.x + v0.y * wq1.x + v0.z * wq2.x + v0.w * wq3.x;
      y0 += v0.x * wq0.y + v0.y * wq1.y + v0.z * wq2.y + v0.w * wq3.y;
      x1 += v1.x * wq0.x + v1.y * wq1.x + v1.z * wq2.x + v1.w * wq3.x;
      y1 += v1.x * wq0.y + v1.y * wq1.y + v1.z * wq2.y + v1.w * wq3.y;
      x2 += v2.x * wq0.x + v2.y * wq1.x + v2.z * wq2.x + v2.w * wq3.x;
      y2 += v2.x * wq0.y + v2.y * wq1.y + v2.z * wq2.y + v2.w * wq3.y;
      x3 += v3.x * wq0.x + v3.y * wq1.x + v3.z * wq2.x + v3.w * wq3.x;
      y3 += v3.x * wq0.y + v3.y * wq1.y + v3.z * wq2.y + v3.w * wq3.y;
    }
    float xs[4] = { x0, x1, x2, x3 }, ys[4] = { y0, y1, y2, y3 };
#pragma unroll
    for (int j = 0; j < 4; ++j) {
      int n = n0 + j;
      float2 st; st.x = xs[j]; st.y = ys[j];
      ((float2*)xw2)[(size_t)n * 64 + lane] = st;
      float ps = xs[j] * asx + ys[j] * asy, pd = xs[j] * adx + ys[j] * ady;
      ps += __shfl_xor(ps, 1); ps += __shfl_xor(ps, 2); ps += __shfl_xor(ps, 4);
      pd += __shfl_xor(pd, 1); pd += __shfl_xor(pd, 2); pd += __shfl_xor(pd, 4);
      if ((lane & 7) == 0) { al2s[n * 8 + (lane >> 3)] = ps; al2d[n * 8 + (lane >> 3)] = pd; }
    }
  }
}

// ---------------- CSR build ----------------
__global__ void count_k(const int* __restrict__ dstA, int* __restrict__ cnt) {
  int e = blockIdx.x * 256 + threadIdx.x;
  if (e < N_EDGES) atomicAdd(&cnt[dstA[e]], 1);
}

__global__ __launch_bounds__(1024) void scan_k(const int* __restrict__ cnt,
    int* __restrict__ rowst, int* __restrict__ cursor)
{
  __shared__ int sums[1024];
  const int tid = threadIdx.x;
  const int CH = (N_NODES + 1023) / 1024;   // 49
  int beg = tid * CH, end = beg + CH; if (end > N_NODES) end = N_NODES;
  int s = 0;
  for (int i = beg; i < end; ++i) s += cnt[i];
  sums[tid] = s;
  __syncthreads();
  for (int off = 1; off < 1024; off <<= 1) {
    int v = (tid >= off) ? sums[tid - off] : 0;
    __syncthreads();
    sums[tid] += v;
    __syncthreads();
  }
  int pre = (tid > 0) ? sums[tid - 1] : 0;
  for (int i = beg; i < end; ++i) {
    rowst[i] = pre; cursor[i] = pre; pre += cnt[i];
  }
}

__global__ void scatter_k(const int* __restrict__ srcA, const int* __restrict__ dstA,
    int* __restrict__ cursor, int* __restrict__ csr)
{
  int e = blockIdx.x * 256 + threadIdx.x;
  if (e < N_EDGES) {
    int d = dstA[e];
    int p = atomicAdd(&cursor[d], 1);
    csr[p] = srcA[e];
  }
}

// ---------------- Layer-1 aggregation: wave per node, NO-max softmax, 4x unrolled ----------------
__global__ __launch_bounds__(256) void agg1_k(const float* __restrict__ xw1,
    const float* __restrict__ al1s, const float* __restrict__ al1d,
    const int* __restrict__ rowst, const int* __restrict__ cnt, const int* __restrict__ csr,
    const float* __restrict__ b1, float* __restrict__ h1, float* __restrict__ denom1)
{
  const int lane = threadIdx.x & 63;
  const int n = blockIdx.x * 4 + (threadIdx.x >> 6);
  if (n >= N_NODES) return;
  const int h = lane >> 3;
  const float ad = al1d[n * 8 + h];
  // self-loop
  float ws = __expf(leaky(al1s[n * 8 + h] + ad));
  float den0 = ws, den1r = 0.f;
  float acc0 = ws * xw1[(size_t)n * 64 + lane], acc1 = 0.f;
  const int beg = rowst[n], num = cnt[n];
  int i = 0;
  for (; i + 4 <= num; i += 4) {
    int s0 = csr[beg + i], s1 = csr[beg + i + 1], s2 = csr[beg + i + 2], s3 = csr[beg + i + 3];
    float l0 = al1s[s0 * 8 + h] + ad, l1 = al1s[s1 * 8 + h] + ad;
    float l2 = al1s[s2 * 8 + h] + ad, l3 = al1s[s3 * 8 + h] + ad;
    float v0 = xw1[(size_t)s0 * 64 + lane], v1 = xw1[(size_t)s1 * 64 + lane];
    float v2 = xw1[(size_t)s2 * 64 + lane], v3 = xw1[(size_t)s3 * 64 + lane];
    float w0 = __expf(leaky(l0)), w1 = __expf(leaky(l1));
    float w2 = __expf(leaky(l2)), w3 = __expf(leaky(l3));
    acc0 += w0 * v0; acc1 += w1 * v1; acc0 += w2 * v2; acc1 += w3 * v3;
    den0 += w0 + w2; den1r += w1 + w3;
  }
  for (; i < num; ++i) {
    int s = csr[beg + i];
    float w = __expf(leaky(al1s[s * 8 + h] + ad));
    acc0 += w * xw1[(size_t)s * 64 + lane];
    den0 += w;
  }
  float den = den0 + den1r, acc = acc0 + acc1;
  if ((lane & 7) == 0) denom1[n * 8 + h] = den;
  float o = acc / (den + 1e-16f) + b1[lane];
  h1[(size_t)n * 64 + lane] = o > 0.f ? o : (__expf(o) - 1.f);   // ELU
}

// ---------------- alpha1 output: one thread per edge, vector loads/stores ----------------
__global__ void alpha_k(const int* __restrict__ srcA, const int* __restrict__ dstA,
    const float* __restrict__ al1s, const float* __restrict__ al1d,
    const float* __restrict__ denom1, float* __restrict__ alpha_out)
{
  int e = blockIdx.x * 256 + threadIdx.x;
  if (e >= N_TOT) return;
  int s, d;
  if (e < N_EDGES) { s = srcA[e]; d = dstA[e]; }
  else             { s = d = e - N_EDGES; }
  float4 as0 = ((const float4*)(al1s + s * 8))[0];
  float4 as1 = ((const float4*)(al1s + s * 8))[1];
  float4 ad0 = ((const float4*)(al1d + d * 8))[0];
  float4 ad1 = ((const float4*)(al1d + d * 8))[1];
  float4 dn0 = ((const float4*)(denom1 + d * 8))[0];
  float4 dn1 = ((const float4*)(denom1 + d * 8))[1];
  float4 o0, o1;
  o0.x = __expf(leaky(as0.x + ad0.x)) / (dn0.x + 1e-16f);
  o0.y = __expf(leaky(as0.y + ad0.y)) / (dn0.y + 1e-16f);
  o0.z = __expf(leaky(as0.z + ad0.z)) / (dn0.z + 1e-16f);
  o0.w = __expf(leaky(as0.w + ad0.w)) / (dn0.w + 1e-16f);
  o1.x = __expf(leaky(as1.x + ad1.x)) / (dn1.x + 1e-16f);
  o1.y = __expf(leaky(as1.y + ad1.y)) / (dn1.y + 1e-16f);
  o1.z = __expf(leaky(as1.z + ad1.z)) / (dn1.z + 1e-16f);
  o1.w = __expf(leaky(as1.w + ad1.w)) / (dn1.w + 1e-16f);
  ((float4*)(alpha_out + (size_t)e * 8))[0] = o0;
  ((float4*)(alpha_out + (size_t)e * 8))[1] = o1;
}

// ---------------- Layer-2 aggregation + log_softmax: wave per node, NO-max, 4x unrolled ----------------
__global__ __launch_bounds__(256) void agg2_k(const float* __restrict__ xw2,
    const float* __restrict__ al2s, const float* __restrict__ al2d,
    const int* __restrict__ rowst, const int* __restrict__ cnt, const int* __restrict__ csr,
    const float* __restrict__ b2, float* __restrict__ logp)
{
  const int lane = threadIdx.x & 63;
  const int n = blockIdx.x * 4 + (threadIdx.x >> 6);
  if (n >= N_NODES) return;
  const int h = lane >> 3;
  const float ad = al2d[n * 8 + h];
  const float2* xwv = (const float2*)xw2;
  float ws = __expf(leaky(al2s[n * 8 + h] + ad));
  float2 a0 = xwv[(size_t)n * 64 + lane];
  float den0 = ws, den1r = 0.f;
  float ax0 = ws * a0.x, ay0 = ws * a0.y, ax1 = 0.f, ay1 = 0.f;
  const int beg = rowst[n], num = cnt[n];
  int i = 0;
  for (; i + 4 <= num; i += 4) {
    int s0 = csr[beg + i], s1 = csr[beg + i + 1], s2 = csr[beg + i + 2], s3 = csr[beg + i + 3];
    float l0 = al2s[s0 * 8 + h] + ad, l1 = al2s[s1 * 8 + h] + ad;
    float l2 = al2s[s2 * 8 + h] + ad, l3 = al2s[s3 * 8 + h] + ad;
    float2 v0 = xwv[(size_t)s0 * 64 + lane], v1 = xwv[(size_t)s1 * 64 + lane];
    float2 v2 = xwv[(size_t)s2 * 64 + lane], v3 = xwv[(size_t)s3 * 64 + lane];
    float w0 = __expf(leaky(l0)), w1 = __expf(leaky(l1));
    float w2 = __expf(leaky(l2)), w3 = __expf(leaky(l3));
    ax0 += w0 * v0.x; ay0 += w0 * v0.y;  ax1 += w1 * v1.x; ay1 += w1 * v1.y;
    ax0 += w2 * v2.x; ay0 += w2 * v2.y;  ax1 += w3 * v3.x; ay1 += w3 * v3.y;
    den0 += w0 + w2; den1r += w1 + w3;
  }
  for (; i < num; ++i) {
    int s = csr[beg + i];
    float w = __expf(leaky(al2s[s * 8 + h] + ad));
    float2 v = xwv[(size_t)s * 64 + lane];
    ax0 += w * v.x; ay0 += w * v.y; den0 += w;
  }
  float inv = 1.f / (den0 + den1r + 1e-16f);
  float o0 = (ax0 + ax1) * inv + b2[2 * lane];
  float o1 = (ay0 + ay1) * inv + b2[2 * lane + 1];
  float mx = fmaxf(o0, o1);
#pragma unroll
  for (int off = 1; off < 64; off <<= 1) mx = fmaxf(mx, __shfl_xor(mx, off));
  float se = __expf(o0 - mx) + __expf(o1 - mx);
#pragma unroll
  for (int off = 1; off < 64; off <<= 1) se += __shfl_xor(se, off);
  float lse = mx + __logf(se);
  float2 o; o.x = o0 - lse; o.y = o1 - lse;
  ((float2*)logp)[(size_t)n * 64 + lane] = o;
}

extern "C" void kernel_launch(void* const* d_in, const int* in_sizes, int n_in,
                              void* d_out, int out_size, void* d_ws, size_t ws_size,
                              hipStream_t stream)
{
  const float* x   = (const float*)d_in[0];
  const int*   ei  = (const int*)d_in[1];
  const float* W1  = (const float*)d_in[2];
  const float* a1s = (const float*)d_in[3];
  const float* a1d = (const float*)d_in[4];
  const float* b1  = (const float*)d_in[5];
  const float* W2  = (const float*)d_in[6];
  const float* a2s = (const float*)d_in[7];
  const float* a2d = (const float*)d_in[8];
  const float* b2  = (const float*)d_in[9];
  const int* srcA = ei;
  const int* dstA = ei + N_EDGES;

  float* ws    = (float*)d_ws;
  float* xw1   = ws;                   // 3,200,000
  float* h1    = xw1 + 3200000;        // 3,200,000
  float* xw2   = h1 + 3200000;         // 6,400,000
  float* al1s_ = xw2 + 6400000;        // 400,000
  float* al1d_ = al1s_ + 400000;
  float* den1_ = al1d_ + 400000;
  float* al2s_ = den1_ + 400000;
  float* al2d_ = al2s_ + 400000;
  int* cnt    = (int*)(al2d_ + 400000);
  int* rowst  = cnt + N_NODES;
  int* cursor = rowst + N_NODES;
  int* csr    = cursor + N_NODES;      // 800,000

  float* logp      = (float*)d_out;
  float* alpha_out = logp + (size_t)N_NODES * 128;

  hipMemsetAsync(cnt, 0, N_NODES * sizeof(int), stream);

  gemm1_k<<<512, 256, 0, stream>>>(x, W1, a1s, a1d, xw1, al1s_, al1d_);
  count_k<<<(N_EDGES + 255) / 256, 256, 0, stream>>>(dstA, cnt);
  scan_k<<<1, 1024, 0, stream>>>(cnt, rowst, cursor);
  scatter_k<<<(N_EDGES + 255) / 256, 256, 0, stream>>>(srcA, dstA, cursor, csr);
  agg1_k<<<(N_NODES + 3) / 4, 256, 0, stream>>>(xw1, al1s_, al1d_, rowst, cnt, csr, b1, h1, den1_);
  gemm2_k<<<1024, 256, 0, stream>>>(h1, W2, a2s, a2d, xw2, al2s_, al2d_);
  alpha_k<<<(N_TOT + 255) / 256, 256, 0, stream>>>(srcA, dstA, al1s_, al1d_, den1_, alpha_out);
  agg2_k<<<(N_NODES + 3) / 4, 256, 0, stream>>>(xw2, al2s_, al2d_, rowst, cnt, csr, b2, logp);
}